// Round 14
// baseline (327.248 us; speedup 1.0000x reference)
//
#include <hip/hip_runtime.h>
#include <hip/hip_bf16.h>

#define BATCH 4
#define SEQ   1024
#define DIM   1024
#define NH    16
#define DH    64
#define DFF   4096
#define MTOK  (BATCH*SEQ)   // 4096 token rows

// log2(e)/8 : folded into Q so attention softmax runs in base-2 (exact).
#define QSCALE 0.1803368801111204f

typedef __attribute__((ext_vector_type(8))) short  short8;
typedef __attribute__((ext_vector_type(4))) short  short4v;
typedef __attribute__((ext_vector_type(4))) float  floatx4;
typedef __attribute__((ext_vector_type(4))) float  float4v;
typedef __attribute__((ext_vector_type(4))) int    int4v;

__device__ inline float bf2f(short s) {
    return __uint_as_float(((unsigned int)(unsigned short)s) << 16);
}
__device__ inline short f2bf(float f) {
    __hip_bfloat16 h = __float2bfloat16(f);
    return *reinterpret_cast<short*>(&h);
}

__device__ inline float wave_sum(float v) {
    #pragma unroll
    for (int off = 32; off >= 1; off >>= 1) v += __shfl_xor(v, off);
    return v;
}

// async global->LDS, 16B per lane; LDS dst = wave-uniform base + lane*16.
__device__ inline void async_ld16(short* lds, const short* g) {
    __builtin_amdgcn_global_load_lds(
        (const __attribute__((address_space(1))) void*)g,
        (__attribute__((address_space(3))) void*)lds, 16, 0, 0);
}

// ---------------------------------------------------------------------------
// Fused fp32->bf16 conversion of all 6 tensors in ONE launch.
// ---------------------------------------------------------------------------
__global__ __launch_bounds__(256) void convert_all(
    const float* __restrict__ sX,  short* __restrict__ dX,
    const float* __restrict__ sq,  short* __restrict__ dq,
    const float* __restrict__ sk,  short* __restrict__ dk,
    const float* __restrict__ sv,  short* __restrict__ dv,
    const float* __restrict__ s1,  short* __restrict__ d1,
    const float* __restrict__ s2,  short* __restrict__ d2)
{
    int cid = blockIdx.x * 256 + threadIdx.x;     // 0 .. 1966079
    const float* src; short* dst; int base;
    if      (cid <  524288) { src = sX; dst = dX; base = 0; }
    else if (cid <  655360) { src = sq; dst = dq; base = 524288; }
    else if (cid <  786432) { src = sk; dst = dk; base = 655360; }
    else if (cid <  917504) { src = sv; dst = dv; base = 786432; }
    else if (cid < 1441792) { src = s1; dst = d1; base = 917504; }
    else                    { src = s2; dst = d2; base = 1441792; }
    size_t i = (size_t)(cid - base) * 8;
    float4v f0 = *(const float4v*)(src + i);
    float4v f1 = *(const float4v*)(src + i + 4);
    short8 o;
    o[0]=f2bf(f0[0]); o[1]=f2bf(f0[1]); o[2]=f2bf(f0[2]); o[3]=f2bf(f0[3]);
    o[4]=f2bf(f1[0]); o[5]=f2bf(f1[1]); o[6]=f2bf(f1[2]); o[7]=f2bf(f1[3]);
    *(short8*)(dst + i) = o;
}

// ---------------------------------------------------------------------------
// NT GEMM, register double-buffer with PREFETCH DEPTH 2 (two static sets,
// loop unrolled x2 -- no dynamic reg indexing): the vmcnt wait for a staged
// tile lands a full iteration + compute (~700cy) after issue.
// For EPI 1/3 the MFMA operands are SWAPPED (computes C^T): the C/D layout
// then gives each lane 4 CONSECUTIVE C-columns of one C-row -> packed 8B
// stores, 16 instead of 64 per thread (cuts epilogue VALU ~4x).
// EPI: 0 = QKV split store (unswapped; Q pre-scaled by QSCALE; V written
//          transposed into Vt[bh][d][key], key-packed)
//      1 = +bias,SELU (swapped)
//      3 = split-K bf16 partial store, blockIdx.z = K quarter (swapped)
// ---------------------------------------------------------------------------
template<int BN, int EPI>
__global__ __launch_bounds__(256) void gemm128(
    const short* __restrict__ A, const short* __restrict__ B,
    const float* __restrict__ bias, const short* __restrict__ resid,
    short* __restrict__ C, int N, int K)
{
    constexpr int NSUB = BN / 32;
    constexpr bool SW  = (EPI == 1 || EPI == 3);
    constexpr int LDA  = 40;                       // padded row stride
    __shared__ __align__(16) short As[128*LDA];    // 10 KB
    __shared__ __align__(16) short Bs[BN*LDA];     // 10 / 5 KB

    const int t    = threadIdx.x;
    const int lane = t & 63;
    const int wave = t >> 6;
    const int quad = lane >> 4;
    const int l15  = lane & 15;
    const int wm   = wave & 1;
    const int wn   = wave >> 1;
    const int tm   = blockIdx.x * 128;
    const int tn   = blockIdx.y * BN;

    int kbase = 0, klen = K;
    if (EPI == 3) { klen = K >> 2; kbase = blockIdx.z * klen; }

    const int srow = t >> 2;           // 0..63
    const int skof = (t & 3) * 8;      // k-offset within 32
    const short* Ag0 = A + (size_t)(tm + srow) * K + kbase + skof;
    const short* Ag1 = Ag0 + (size_t)64 * K;
    const short* Bg0 = B + (size_t)(tn + srow) * K + kbase + skof;
    const short* Bg1 = Bg0 + (size_t)64 * K;

    short* Aw0 = &As[srow*LDA + skof];
    short* Aw1 = &As[(64 + srow)*LDA + skof];
    short* Bw0 = &Bs[srow*LDA + skof];
    short* Bw1 = (BN == 128) ? &Bs[(64 + srow)*LDA + skof] : nullptr;

    floatx4 acc[4][NSUB];
    #pragma unroll
    for (int mt = 0; mt < 4; mt++)
        #pragma unroll
        for (int nt = 0; nt < NSUB; nt++) acc[mt][nt] = {0.f, 0.f, 0.f, 0.f};

    // two static prefetch register sets
    int4v a0A, a1A, b0A, b1A;          // set 0
    int4v a0B, a1B, b0B, b1B;          // set 1

    auto load0 = [&](int k0) {
        a0A = *(const int4v*)(Ag0 + k0); a1A = *(const int4v*)(Ag1 + k0);
        b0A = *(const int4v*)(Bg0 + k0);
        if (BN == 128) b1A = *(const int4v*)(Bg1 + k0);
    };
    auto load1 = [&](int k0) {
        a0B = *(const int4v*)(Ag0 + k0); a1B = *(const int4v*)(Ag1 + k0);
        b0B = *(const int4v*)(Bg0 + k0);
        if (BN == 128) b1B = *(const int4v*)(Bg1 + k0);
    };
    auto write0 = [&]() {
        *(int4v*)Aw0 = a0A; *(int4v*)Aw1 = a1A;
        *(int4v*)Bw0 = b0A;
        if (BN == 128) *(int4v*)Bw1 = b1A;
    };
    auto write1 = [&]() {
        *(int4v*)Aw0 = a0B; *(int4v*)Aw1 = a1B;
        *(int4v*)Bw0 = b0B;
        if (BN == 128) *(int4v*)Bw1 = b1B;
    };
    auto compute = [&]() {
        short8 a[4], b[NSUB];
        #pragma unroll
        for (int mt = 0; mt < 4; mt++)
            a[mt] = *(const short8*)&As[(wm*64 + mt*16 + l15)*LDA + quad*8];
        #pragma unroll
        for (int nt = 0; nt < NSUB; nt++)
            b[nt] = *(const short8*)&Bs[(wn*(BN/2) + nt*16 + l15)*LDA + quad*8];
        #pragma unroll
        for (int mt = 0; mt < 4; mt++)
            #pragma unroll
            for (int nt = 0; nt < NSUB; nt++)
                acc[mt][nt] = SW
                    ? __builtin_amdgcn_mfma_f32_16x16x32_bf16(
                          b[nt], a[mt], acc[mt][nt], 0, 0, 0)
                    : __builtin_amdgcn_mfma_f32_16x16x32_bf16(
                          a[mt], b[nt], acc[mt][nt], 0, 0, 0);
    };

    // prologue: tile0 -> LDS, tile1 in flight    (klen is a multiple of 64)
    load0(0);
    write0();
    __syncthreads();
    load1(32);

    for (int k0 = 0; k0 < klen; k0 += 64) {
        if (k0 + 64 < klen) load0(k0 + 64);
        compute();                         // tile k0
        __syncthreads();
        write1();                          // tile k0+32 -> LDS
        __syncthreads();
        if (k0 + 96 < klen) load1(k0 + 96);
        compute();                         // tile k0+32
        __syncthreads();
        if (k0 + 64 < klen) { write0(); }
        __syncthreads();
    }

    const float SS = 1.0507009873554805f;
    const float SA = 1.6732632423543772f;

    if (SW) {
        // swapped layout: lane -> row = ...+l15 ; regs r -> 4 consecutive cols
        #pragma unroll
        for (int mt = 0; mt < 4; mt++) {
            int row = tm + wm*64 + mt*16 + l15;
            #pragma unroll
            for (int nt = 0; nt < NSUB; nt++) {
                int col0 = tn + wn*(BN/2) + nt*16 + quad*4;
                short4v pv;
                if (EPI == 1) {
                    float4v bb = *(const float4v*)(bias + col0);
                    #pragma unroll
                    for (int r = 0; r < 4; r++) {
                        float v = acc[mt][nt][r] + bb[r];
                        v = (v > 0.f) ? SS * v
                                      : SS * SA * (exp2f(v * 1.44269504f) - 1.f);
                        pv[r] = f2bf(v);
                    }
                    *(short4v*)&C[(size_t)row * N + col0] = pv;
                } else {   // EPI == 3
                    #pragma unroll
                    for (int r = 0; r < 4; r++) pv[r] = f2bf(acc[mt][nt][r]);
                    *(short4v*)&C[(size_t)blockIdx.z * ((size_t)MTOK*N)
                                  + (size_t)row * N + col0] = pv;
                }
            }
        }
    } else {
        #pragma unroll
        for (int mt = 0; mt < 4; mt++) {
            #pragma unroll
            for (int nt = 0; nt < NSUB; nt++) {
                int col = tn + wn*(BN/2) + nt*16 + l15;
                if (EPI == 0 && (col >> 10) == 2) {
                    // V: packed transposed store -> Vt[bh][d][key]
                    int h = (col >> 6) & 15, d = col & 63;
                    int row0 = tm + wm*64 + mt*16 + quad*4;
                    int b = row0 >> 10, key = row0 & 1023;
                    short4v pv;
                    #pragma unroll
                    for (int r = 0; r < 4; r++) pv[r] = f2bf(acc[mt][nt][r]);
                    *(short4v*)&C[(size_t)2*MTOK*1024
                        + ((size_t)(b*16 + h)*64 + d)*1024 + key] = pv;
                    continue;
                }
                #pragma unroll
                for (int r = 0; r < 4; r++) {
                    int row = tm + wm*64 + mt*16 + quad*4 + r;
                    float v = acc[mt][nt][r];
                    int which = col >> 10;
                    if (which == 0) v *= QSCALE;   // base-2 softmax fold
                    C[(size_t)which * ((size_t)MTOK*1024)
                      + (size_t)row * 1024 + (col & 1023)] = f2bf(v);
                }
            }
        }
    }
}

// ---------------------------------------------------------------------------
// MFMA flash attention, 128-row Q-tile, ping-pong LDS-staged K/V.
// Base-2 fixed-m softmax, ones-MFMA row-sum. V pre-transposed by QKV
// epilogue (Vt[bh][d][key]). Grid = (SEQ/128, BATCH*NH).
// ---------------------------------------------------------------------------
__global__ __launch_bounds__(256) void attn_kernel(
    const short* __restrict__ Q, const short* __restrict__ K,
    const short* __restrict__ Vt, short* __restrict__ CTX)
{
    __shared__ __align__(16) short Ks[2][64*64];    // [key][d], 2 x 8 KB
    __shared__ __align__(16) short Vs[2][64*64];    // [d][key], 2 x 8 KB
    __shared__ __align__(16) short Pl[4][32][72];   // [wave][qrow][key], 18 KB

    const int t    = threadIdx.x;
    const int lane = t & 63;
    const int wave = t >> 6;
    const int quad = lane >> 4;
    const int l15  = lane & 15;
    const int q0 = (gridDim.x - 1 - blockIdx.x) * 128;   // long blocks first
    const int bh = blockIdx.y;
    const int b  = bh >> 4;
    const int h  = bh & 15;

    const size_t headoff = (size_t)b * SEQ * DIM + (size_t)h * DH;
    const short* Qb  = Q + headoff;
    const short* Kb  = K + headoff;
    const short* Vtb = Vt + (size_t)bh * DH * SEQ;   // [d][key]

    const int wrow0 = q0 + wave*32;                  // wave's first q-row

    short8 aq[2][2];
    #pragma unroll
    for (int mg = 0; mg < 2; mg++)
        #pragma unroll
        for (int c = 0; c < 2; c++)
            aq[mg][c] = *(const short8*)(Qb
                + (size_t)(wrow0 + mg*16 + l15) * DIM + c*32 + quad*8);

    short8 bones;
    {
        short v = (l15 == 0) ? (short)0x3F80 : (short)0;
        #pragma unroll
        for (int e = 0; e < 8; e++) bones[e] = v;
    }

    floatx4 o[2][4], ol[2];
    #pragma unroll
    for (int mg = 0; mg < 2; mg++) {
        #pragma unroll
        for (int nt = 0; nt < 4; nt++) o[mg][nt] = {0.f, 0.f, 0.f, 0.f};
        ol[mg] = {0.f, 0.f, 0.f, 0.f};
    }

    auto stage = [&](int j0, int sb) {
        #pragma unroll
        for (int p = 0; p < 2; p++) {
            async_ld16(Ks[sb] + (t + p*256)*8,
                       Kb + (size_t)(j0 + (t>>3) + p*32) * DIM + (t&7)*8);
            async_ld16(Vs[sb] + (t + p*256)*8,
                       Vtb + (size_t)((t>>3) + p*32) * SEQ + j0 + (t&7)*8);
        }
    };

    const int jend = q0 + 128;
    stage(0, 0);
    __syncthreads();

    int sb = 0;
    for (int j0 = 0; j0 < jend; j0 += 64) {
        if (j0 + 64 < jend) stage(j0 + 64, sb ^ 1);

        if (j0 <= wrow0 + 31) {              // not fully masked for this wave
            floatx4 s[2][4];
            #pragma unroll
            for (int mg = 0; mg < 2; mg++)
                #pragma unroll
                for (int nt = 0; nt < 4; nt++) s[mg][nt] = {0.f, 0.f, 0.f, 0.f};
            #pragma unroll
            for (int c = 0; c < 2; c++) {
                #pragma unroll
                for (int nt = 0; nt < 4; nt++) {
                    short8 bk = *(const short8*)&Ks[sb][(nt*16 + l15)*64 + c*32 + quad*8];
                    s[0][nt] = __builtin_amdgcn_mfma_f32_16x16x32_bf16(aq[0][c], bk, s[0][nt], 0, 0, 0);
                    s[1][nt] = __builtin_amdgcn_mfma_f32_16x16x32_bf16(aq[1][c], bk, s[1][nt], 0, 0, 0);
                }
            }

            if (j0 + 63 > wrow0) {           // diagonal region: causal mask
                #pragma unroll
                for (int mg = 0; mg < 2; mg++) {
                    #pragma unroll
                    for (int nt = 0; nt < 4; nt++) {
                        int col = j0 + nt*16 + l15;
                        #pragma unroll
                        for (int r = 0; r < 4; r++) {
                            int rowq = wrow0 + mg*16 + quad*4 + r;
                            if (col > rowq) s[mg][nt][r] = -1.0e38f;
                        }
                    }
                }
            }

            #pragma unroll
            for (int mg = 0; mg < 2; mg++)
                #pragma unroll
                for (int nt = 0; nt < 4; nt++)
                    #pragma unroll
                    for (int r = 0; r < 4; r++)
                        Pl[wave][mg*16 + quad*4 + r][nt*16 + l15]
                            = f2bf(exp2f(s[mg][nt][r]));

            #pragma unroll
            for (int c = 0; c < 2; c++) {
                short8 ap0 = *(const short8*)&Pl[wave][l15][c*32 + quad*8];
                short8 ap1 = *(const short8*)&Pl[wave][16 + l15][c*32 + quad*8];
                #pragma unroll
                for (int nt = 0; nt < 4; nt++) {
                    short8 bv = *(const short8*)&Vs[sb][(nt*16 + l15)*64 + c*32 + quad*8];
                    o[0][nt] = __builtin_amdgcn_mfma_f32_16x16x32_bf16(ap0, bv, o[0][nt], 0, 0, 0);
                    o[1][nt] = __builtin_amdgcn_mfma_f32_16x16x32_bf16(ap1, bv, o[1][nt], 0, 0, 0);
                }
                ol[0] = __builtin_amdgcn_mfma_f32_16x16x32_bf16(ap0, bones, ol[0], 0, 0, 0);
                ol[1] = __builtin_amdgcn_mfma_f32_16x16x32_bf16(ap1, bones, ol[1], 0, 0, 0);
            }
        }

        __syncthreads();                     // drains vmcnt after compute
        sb ^= 1;
    }

    #pragma unroll
    for (int mg = 0; mg < 2; mg++) {
        float linv[4];
        #pragma unroll
        for (int r = 0; r < 4; r++)
            linv[r] = 1.f / __shfl(ol[mg][r], lane & 48);
        #pragma unroll
        for (int nt = 0; nt < 4; nt++) {
            #pragma unroll
            for (int r = 0; r < 4; r++) {
                int rowq = wrow0 + mg*16 + quad*4 + r;
                int d    = nt*16 + l15;
                CTX[(size_t)b * SEQ * DIM + (size_t)rowq * DIM + h*DH + d]
                    = f2bf(o[mg][nt][r] * linv[r]);
            }
        }
    }
}

// ---------------------------------------------------------------------------
// LN1: row LayerNorm over D=1024 of (X fp32 + CTX bf16), bf16 out.
// ---------------------------------------------------------------------------
__global__ __launch_bounds__(256) void ln1_kernel(
    const float* __restrict__ X, const short* __restrict__ ctx,
    const float* __restrict__ g, const float* __restrict__ bvec,
    short* __restrict__ out)
{
    __shared__ float red[8];
    const size_t base = (size_t)blockIdx.x * DIM;
    const int wave = threadIdx.x >> 6;

    float x[4];
    float sum = 0.f, sq = 0.f;
    #pragma unroll
    for (int i = 0; i < 4; i++) {
        int idx = threadIdx.x + i*256;
        float v = X[base + idx] + bf2f(ctx[base + idx]);
        x[i] = v; sum += v; sq += v*v;
    }
    sum = wave_sum(sum); sq = wave_sum(sq);
    if ((threadIdx.x & 63) == 0) { red[wave] = sum; red[4 + wave] = sq; }
    __syncthreads();
    float s1 = red[0] + red[1] + red[2] + red[3];
    float s2 = red[4] + red[5] + red[6] + red[7];
    float mean = s1 * (1.f / DIM);
    float var  = s2 * (1.f / DIM) - mean * mean;
    float rstd = rsqrtf(var + 1e-5f);
    #pragma unroll
    for (int i = 0; i < 4; i++) {
        int idx = threadIdx.x + i*256;
        out[base + idx] = f2bf((x[i] - mean) * rstd * g[idx] + bvec[idx]);
    }
}

// ---------------------------------------------------------------------------
// LN2 fused with split-K reduce: x = P0+P1+P2+P3 (bf16 partials) + bias +
// X1 (residual), then LayerNorm, fp32 out to d_out.
// ---------------------------------------------------------------------------
__global__ __launch_bounds__(256) void ln2_fused(
    const short* __restrict__ P, const float* __restrict__ bias,
    const short* __restrict__ x1, const float* __restrict__ g,
    const float* __restrict__ bvec, float* __restrict__ out)
{
    __shared__ float red[8];
    const size_t base = (size_t)blockIdx.x * DIM;
    const size_t E4 = (size_t)MTOK * 1024;
    const int wave = threadIdx.x >> 6;

    float x[4];
    float sum = 0.f, sq = 0.f;
    #pragma unroll
    for (int i = 0; i < 4; i++) {
        int idx = threadIdx.x + i*256;
        size_t p = base + idx;
        float v = bf2f(P[p]) + bf2f(P[E4 + p]) + bf2f(P[2*E4 + p])
                + bf2f(P[3*E4 + p]) + bias[idx] + bf2f(x1[p]);
        x[i] = v; sum += v; sq += v*v;
    }
    sum = wave_sum(sum); sq = wave_sum(sq);
    if ((threadIdx.x & 63) == 0) { red[wave] = sum; red[4 + wave] = sq; }
    __syncthreads();
    float s1 = red[0] + red[1] + red[2] + red[3];
    float s2 = red[4] + red[5] + red[6] + red[7];
    float mean = s1 * (1.f / DIM);
    float var  = s2 * (1.f / DIM) - mean * mean;
    float rstd = rsqrtf(var + 1e-5f);
    #pragma unroll
    for (int i = 0; i < 4; i++) {
        int idx = threadIdx.x + i*256;
        out[base + idx] = (x[i] - mean) * rstd * g[idx] + bvec[idx];
    }
}

// ---------------------------------------------------------------------------
// Workspace (102 MB -- exactly R2's proven-safe footprint).
// Q | K | Vt contiguous (fused QKV epilogue). P = 4 split-K partials.
// d_out is float* (verified round 4).
// ---------------------------------------------------------------------------
extern "C" void kernel_launch(void* const* d_in, const int* in_sizes, int n_in,
                              void* d_out, int out_size, void* d_ws, size_t ws_size,
                              hipStream_t stream)
{
    const float* X   = (const float*)d_in[0];
    const float* wq  = (const float*)d_in[1];
    const float* wk  = (const float*)d_in[2];
    const float* wv  = (const float*)d_in[3];
    const float* g1  = (const float*)d_in[4];
    const float* b1  = (const float*)d_in[5];
    const float* w1  = (const float*)d_in[6];
    const float* bb1 = (const float*)d_in[7];
    const float* w2  = (const float*)d_in[8];
    const float* bb2 = (const float*)d_in[9];
    const float* g2  = (const float*)d_in[10];
    const float* b2  = (const float*)d_in[11];

    short* ws = (short*)d_ws;
    const size_t E1 = 1048576, E4 = 4194304;
    size_t o = 0;
    short* Xb    = ws + o; o += E4;
    short* wqkvb = ws + o; o += 3*E1;
    short* w1b   = ws + o; o += E4;
    short* w2b   = ws + o; o += E4;
    short* Q     = ws + o; o += E4;   // Q | K | Vt contiguous
    short* Kb    = ws + o; o += E4;
    short* Vt    = ws + o; o += E4;
    short* CTX   = ws + o; o += E4;
    short* X1    = ws + o; o += E4;
    short* P     = ws + o; o += 4*E4; // split-K=4 partials (bf16)
    short* Hf    = Q;                 // 16M elems, overlays Q..CTX

    dim3 blk(256);
    convert_all<<<dim3(7680), blk, 0, stream>>>(
        X, Xb, wq, wqkvb, wk, wqkvb + E1, wv, wqkvb + 2*E1,
        w1, w1b, w2, w2b);

    gemm128<128,0><<<dim3(MTOK/128, 3072/128), blk, 0, stream>>>(
        Xb, wqkvb, nullptr, nullptr, Q, 3072, DIM);
    attn_kernel<<<dim3(SEQ/128, BATCH*NH), blk, 0, stream>>>(Q, Kb, Vt, CTX);
    ln1_kernel<<<dim3(MTOK), blk, 0, stream>>>(X, CTX, g1, b1, X1);
    gemm128<128,1><<<dim3(MTOK/128, DFF/128), blk, 0, stream>>>(
        X1, w1b, bb1, nullptr, Hf, DFF, DIM);
    gemm128<128,3><<<dim3(MTOK/128, DIM/128, 4), blk, 0, stream>>>(
        Hf, w2b, nullptr, nullptr, P, DIM, DFF);
    ln2_fused<<<dim3(MTOK), blk, 0, stream>>>(P, bb2, X1, g2, b2, (float*)d_out);
}